// Round 5
// baseline (535.523 us; speedup 1.0000x reference)
//
#include <hip/hip_runtime.h>
#include <hip/hip_bf16.h>
#include <math.h>

// Problem constants
#define T_SEQ 4096
#define NEMB  2048
#define NH    16
#define NKV   4
#define HD    128
#define WIN   1024

typedef __attribute__((ext_vector_type(8))) __bf16 bf16x8;
typedef __attribute__((ext_vector_type(4))) float  f32x4;

// async global->LDS, 16B per lane; dest = wave-uniform base + lane*16
#define GLOAD_LDS16(gp, lp)                                          \
  __builtin_amdgcn_global_load_lds(                                  \
      (const __attribute__((address_space(1))) void*)(gp),           \
      (__attribute__((address_space(3))) void*)(lp), 16, 0, 0)

__device__ __forceinline__ float wave_sum64(float v) {
#pragma unroll
  for (int off = 1; off < 64; off <<= 1) v += __shfl_xor(v, off, 64);
  return v;
}
__device__ __forceinline__ float wave_max64(float v) {
#pragma unroll
  for (int off = 1; off < 64; off <<= 1) v = fmaxf(v, __shfl_xor(v, off, 64));
  return v;
}

// ---- cast+split x: xsplit[4096][4096] = [x_hi | x_lo], 8 elems/thread ----
__global__ __launch_bounds__(256) void cast_x_split_kernel(const float* __restrict__ src,
                                                           __bf16* __restrict__ dst) {
  int i = blockIdx.x * 256 + threadIdx.x;   // 1M groups of 8
  int row = i >> 8, colg = i & 255;         // 256 groups per 2048-col row
  const f32x4* s4 = (const f32x4*)src;
  f32x4 a = s4[2 * i], b = s4[2 * i + 1];
  bf16x8 hi, lo;
#pragma unroll
  for (int j = 0; j < 4; ++j) {
    hi[j] = (__bf16)a[j]; lo[j] = (__bf16)(a[j] - (float)hi[j]);
    hi[j + 4] = (__bf16)b[j]; lo[j + 4] = (__bf16)(b[j] - (float)hi[j + 4]);
  }
  *(bf16x8*)(dst + (size_t)row * 4096 + colg * 8) = hi;
  *(bf16x8*)(dst + (size_t)row * 4096 + 2048 + colg * 8) = lo;
}

// ------- transpose-cast: src f32 [K=2048][N] -> dst bf16 [N][2048] ------------
__global__ __launch_bounds__(64) void transpose_cast_kernel(const float* __restrict__ src,
                                                            __bf16* __restrict__ dst,
                                                            int K, int N) {
  int kc = blockIdx.x * 8;
  int n  = blockIdx.y * 64 + threadIdx.x;
  bf16x8 o;
#pragma unroll
  for (int j = 0; j < 8; ++j) o[j] = (__bf16)src[(size_t)(kc + j) * N + n];
  *(bf16x8*)(dst + (size_t)n * K + kc) = o;
}

// ---- transpose-split-cast: src f32 [2048][N] -> dst[n][0:2048]=hi,
// ---- dst[n][2048:4096]=hi, dst[n][4096:6144]=lo  (row stride ld=6144) ----
__global__ __launch_bounds__(64) void transpose_split_kernel(const float* __restrict__ src,
                                                             __bf16* __restrict__ dst,
                                                             int N) {
  int kc = blockIdx.x * 8;
  int n  = blockIdx.y * 64 + threadIdx.x;
  bf16x8 hi, lo;
#pragma unroll
  for (int j = 0; j < 8; ++j) {
    float v = src[(size_t)(kc + j) * N + n];
    hi[j] = (__bf16)v; lo[j] = (__bf16)(v - (float)hi[j]);
  }
  *(bf16x8*)(dst + (size_t)n * 6144 + kc) = hi;
  *(bf16x8*)(dst + (size_t)n * 6144 + 2048 + kc) = hi;
  *(bf16x8*)(dst + (size_t)n * 6144 + 4096 + kc) = lo;
}

// ---------------- bf16 MFMA GEMM: C[M,N] = A[M,K] * BT[N,K]^T ----------------
// m97 structure: 128x128 tile, BK=64, 4 waves (2x2), 4x4 frags/wave,
// LINEAR LDS + global_load_lds width=16 staging (no VGPR round-trip).
template <bool OUT_BF16>
__global__ __launch_bounds__(256) void gemm_kernel(const __bf16* __restrict__ A,
                                                   const __bf16* __restrict__ BT,
                                                   void* __restrict__ Cout,
                                                   int M, int N, int K,
                                                   int lda, int ldb, int awrap) {
  __shared__ __align__(16) __bf16 As[128 * 64];  // [row][col] linear
  __shared__ __align__(16) __bf16 Bs[128 * 64];
  const int tid = threadIdx.x;
  const int lane = tid & 63, w = tid >> 6;
  const int wr = w >> 1, wc = w & 1;
  const int g = lane >> 4, c = lane & 15;
  const int m0 = blockIdx.y * 128, n0 = blockIdx.x * 128;
  const int srow = lane >> 3;   // row within 8-row chunk
  const int scol = lane & 7;    // 16B column group
  f32x4 acc[4][4] = {};
  for (int k0 = 0; k0 < K; k0 += 64) {
    int ka = k0 + scol * 8;
    int kaw = (ka >= awrap) ? ka - awrap : ka;
    __syncthreads();            // prev-iter LDS reads done before overwrite
#pragma unroll
    for (int i = 0; i < 4; ++i) {
      int chunk = w * 4 + i;               // 16 chunks of 8 rows
      int row = chunk * 8 + srow;
      GLOAD_LDS16(A  + (size_t)(m0 + row) * lda + kaw, As + chunk * 512);
      GLOAD_LDS16(BT + (size_t)(n0 + row) * ldb + ka,  Bs + chunk * 512);
    }
    __syncthreads();            // compiler drains vmcnt before barrier
#pragma unroll
    for (int kk = 0; kk < 2; ++kk) {
      bf16x8 af[4], bfr[4];
#pragma unroll
      for (int mi = 0; mi < 4; ++mi)
        af[mi] = *(const bf16x8*)&As[(wr * 64 + mi * 16 + c) * 64 + (kk * 4 + g) * 8];
#pragma unroll
      for (int ni = 0; ni < 4; ++ni)
        bfr[ni] = *(const bf16x8*)&Bs[(wc * 64 + ni * 16 + c) * 64 + (kk * 4 + g) * 8];
#pragma unroll
      for (int mi = 0; mi < 4; ++mi)
#pragma unroll
        for (int ni = 0; ni < 4; ++ni)
          acc[mi][ni] = __builtin_amdgcn_mfma_f32_16x16x32_bf16(af[mi], bfr[ni], acc[mi][ni], 0, 0, 0);
    }
  }
  // C frag layout: col = lane&15, row = (lane>>4)*4 + r   [m89-verified]
#pragma unroll
  for (int mi = 0; mi < 4; ++mi) {
#pragma unroll
    for (int ni = 0; ni < 4; ++ni) {
      int row = m0 + wr * 64 + mi * 16 + g * 4;
      int col = n0 + wc * 64 + ni * 16 + c;
#pragma unroll
      for (int r = 0; r < 4; ++r) {
        if constexpr (OUT_BF16)
          ((__bf16*)Cout)[(size_t)(row + r) * N + col] = (__bf16)acc[mi][ni][r];
        else
          ((float*)Cout)[(size_t)(row + r) * N + col] = acc[mi][ni][r];
      }
    }
  }
}

// -------- RoPE + RMSNorm (q,k) + quant-dequant (k,v), v stored transposed --------
__global__ __launch_bounds__(256) void rope_norm_quant_kernel(const __bf16* __restrict__ qproj,
                                                              const float* __restrict__ kvproj,
                                                              const float* __restrict__ cosp,
                                                              const float* __restrict__ sinp,
                                                              __bf16* __restrict__ qb,
                                                              __bf16* __restrict__ kb,
                                                              __bf16* __restrict__ vt) {
  const int t = blockIdx.x;
  const int w = threadIdx.x >> 6, lane = threadIdx.x & 63;
  const int slot = blockIdx.y * 4 + w;
  float a, b;
  if (slot < 16) {
    const __bf16* base = qproj + (size_t)t * 2048 + slot * 128;
    a = (float)base[lane]; b = (float)base[lane + 64];
  } else {
    const float* base = kvproj + (size_t)t * 1024 + (slot - 16) * 128;
    a = base[lane]; b = base[lane + 64];
  }
  float o1, o2;
  if (slot < 20) {  // rope + rmsnorm for q and k
    float cv = cosp[t * 64 + lane], sv = sinp[t * 64 + lane];
    o1 = a * cv + b * sv;
    o2 = -a * sv + b * cv;
    float ss = wave_sum64(o1 * o1 + o2 * o2);
    float sc = rsqrtf(ss * (1.0f / 128.0f) + 1.1920929e-7f);
    o1 *= sc; o2 *= sc;
  } else { o1 = a; o2 = b; }
  if (slot < 16) {
    __bf16* dst = qb + ((size_t)slot * T_SEQ + t) * HD;
    dst[lane] = (__bf16)o1; dst[lane + 64] = (__bf16)o2;
  } else {
    float amax = wave_max64(fmaxf(fabsf(o1), fabsf(o2)));
    float s = fmaxf(amax * (1.0f / 3.0f), 1e-8f);
    float d1 = fminf(fmaxf(rintf(o1 / s), -3.0f), 3.0f) * s;
    float d2 = fminf(fmaxf(rintf(o2 / s), -3.0f), 3.0f) * s;
    if (slot < 20) {
      __bf16* dst = kb + ((size_t)(slot - 16) * T_SEQ + t) * HD;
      dst[lane] = (__bf16)d1; dst[lane + 64] = (__bf16)d2;
    } else {
      __bf16* dst = vt + (size_t)(slot - 20) * HD * T_SEQ;   // [hkv][d][t]
      dst[(size_t)lane * T_SEQ + t]        = (__bf16)d1;
      dst[(size_t)(lane + 64) * T_SEQ + t] = (__bf16)d2;
    }
  }
}

// ------- flash sliding-window attention, window-split across 2 waves -------
// Block = 128 threads (2 waves) per 32-row q-tile. Wave w takes half the
// ~33 key-steps. No max-tracking (RMSNorm bounds scores; exp is exact under
// softmax shift-invariance), so the cross-wave combine is a PURE SUM of
// unnormalized O-partials + row-sums: wave1 -> LDS f32, wave0 adds+normalizes.
__global__ __launch_bounds__(128) void attn_kernel(const __bf16* __restrict__ qb,
                                                   const __bf16* __restrict__ kb,
                                                   const __bf16* __restrict__ vt,
                                                   __bf16* __restrict__ attn) {
  __shared__ __align__(16) __bf16 plds[2][32][40];  // per-wave P tile
  __shared__ __align__(16) float comb[128][36];     // [col][row], pad 36: 2-way banks
  __shared__ __align__(16) float lsumL[32];
  const int w = threadIdx.x >> 6, lane = threadIdx.x & 63;
  const int g = lane >> 4, c = lane & 15;
  const int tile = blockIdx.x;          // 0..2047
  const int h = tile >> 7, qt = tile & 127;
  const int q0 = qt * 32;
  const int hkv = h >> 2;
  const __bf16* kbase = kb + (size_t)hkv * T_SEQ * HD;
  const __bf16* vbase = vt + (size_t)hkv * HD * T_SEQ;
  const float scl = 0.08838834764831845f;  // 1/sqrt(128)

  bf16x8 qf[2][4];
#pragma unroll
  for (int mi = 0; mi < 2; ++mi)
#pragma unroll
    for (int kc = 0; kc < 4; ++kc)
      qf[mi][kc] = *(const bf16x8*)(qb + ((size_t)h * T_SEQ + q0 + 16 * mi + c) * HD + kc * 32 + 8 * g);

  f32x4 acc[2][8] = {};
  float lsum[2][4] = {};

  int lo = q0 - (WIN - 1);
  if (lo < 0) lo = 0;
  lo &= ~31;
  const int nst = (q0 - lo) / 32 + 1;   // total steps (1..33)
  const int nh = nst >> 1;
  const int s0 = w ? nh : 0;
  const int s1 = w ? nst : nh;
  for (int si = s0; si < s1; ++si) {
    const int kj0 = lo + si * 32;
    f32x4 s[2][2] = {};
#pragma unroll
    for (int kc = 0; kc < 4; ++kc) {
      bf16x8 bk0 = *(const bf16x8*)(kbase + (size_t)(kj0 + c) * HD + kc * 32 + 8 * g);
      bf16x8 bk1 = *(const bf16x8*)(kbase + (size_t)(kj0 + 16 + c) * HD + kc * 32 + 8 * g);
#pragma unroll
      for (int mi = 0; mi < 2; ++mi) {
        s[mi][0] = __builtin_amdgcn_mfma_f32_16x16x32_bf16(qf[mi][kc], bk0, s[mi][0], 0, 0, 0);
        s[mi][1] = __builtin_amdgcn_mfma_f32_16x16x32_bf16(qf[mi][kc], bk1, s[mi][1], 0, 0, 0);
      }
    }
    float p[2][2][4];
#pragma unroll
    for (int mi = 0; mi < 2; ++mi)
#pragma unroll
      for (int ni = 0; ni < 2; ++ni)
#pragma unroll
        for (int r = 0; r < 4; ++r) {
          int qrow = q0 + 16 * mi + 4 * g + r;
          int kcol = kj0 + 16 * ni + c;
          int d = qrow - kcol;
          float e = __expf(s[mi][ni][r] * scl);
          p[mi][ni][r] = (d >= 0 && d < WIN) ? e : 0.0f;
        }
#pragma unroll
    for (int mi = 0; mi < 2; ++mi)
#pragma unroll
      for (int r = 0; r < 4; ++r)
        lsum[mi][r] += p[mi][0][r] + p[mi][1][r];
    // P (C-frag) -> LDS -> PV A-frag
#pragma unroll
    for (int mi = 0; mi < 2; ++mi)
#pragma unroll
      for (int ni = 0; ni < 2; ++ni)
#pragma unroll
        for (int r = 0; r < 4; ++r)
          plds[w][16 * mi + 4 * g + r][16 * ni + c] = (__bf16)p[mi][ni][r];
    asm volatile("s_waitcnt lgkmcnt(0)" ::: "memory");
    __builtin_amdgcn_sched_barrier(0);
    bf16x8 pa[2];
#pragma unroll
    for (int mi = 0; mi < 2; ++mi) pa[mi] = *(const bf16x8*)&plds[w][16 * mi + c][8 * g];
#pragma unroll
    for (int df = 0; df < 8; ++df) {
      bf16x8 bv = *(const bf16x8*)(vbase + (size_t)(df * 16 + c) * T_SEQ + kj0 + 8 * g);
#pragma unroll
      for (int mi = 0; mi < 2; ++mi)
        acc[mi][df] = __builtin_amdgcn_mfma_f32_16x16x32_bf16(pa[mi], bv, acc[mi][df], 0, 0, 0);
    }
    asm volatile("" ::: "memory");
  }
  // 16-lane row-sum reduce in both waves
#pragma unroll
  for (int mi = 0; mi < 2; ++mi)
#pragma unroll
    for (int off = 1; off < 16; off <<= 1)
#pragma unroll
      for (int r = 0; r < 4; ++r) lsum[mi][r] += __shfl_xor(lsum[mi][r], off, 64);
  if (w == 1) {  // publish partials
#pragma unroll
    for (int mi = 0; mi < 2; ++mi) {
#pragma unroll
      for (int df = 0; df < 8; ++df)
        *(f32x4*)&comb[df * 16 + c][16 * mi + 4 * g] = acc[mi][df];
      if (c == 0) {
        f32x4 t;
#pragma unroll
        for (int r = 0; r < 4; ++r) t[r] = lsum[mi][r];
        *(f32x4*)&lsumL[16 * mi + 4 * g] = t;
      }
    }
  }
  __syncthreads();
  if (w == 0) {  // merge, normalize, store
#pragma unroll
    for (int mi = 0; mi < 2; ++mi) {
      f32x4 lw = *(const f32x4*)&lsumL[16 * mi + 4 * g];
      float inv[4];
#pragma unroll
      for (int r = 0; r < 4; ++r) inv[r] = 1.0f / (lsum[mi][r] + lw[r]);
#pragma unroll
      for (int df = 0; df < 8; ++df) {
        f32x4 cv = *(const f32x4*)&comb[df * 16 + c][16 * mi + 4 * g];
#pragma unroll
        for (int r = 0; r < 4; ++r) {
          float v = (acc[mi][df][r] + cv[r]) * inv[r];
          attn[(size_t)(q0 + 16 * mi + 4 * g + r) * NEMB + h * HD + df * 16 + c] = (__bf16)v;
        }
      }
    }
  }
}

extern "C" void kernel_launch(void* const* d_in, const int* in_sizes, int n_in,
                              void* d_out, int out_size, void* d_ws, size_t ws_size,
                              hipStream_t stream) {
  (void)in_sizes; (void)n_in; (void)out_size; (void)ws_size;
  const float* x    = (const float*)d_in[0];
  const float* cosp = (const float*)d_in[1];
  const float* sinp = (const float*)d_in[2];
  const float* Wq   = (const float*)d_in[3];
  const float* Wk   = (const float*)d_in[4];
  const float* Wv   = (const float*)d_in[5];
  const float* Wo   = (const float*)d_in[6];

  // workspace layout (bytes); total = 121,634,816
  char* ws = (char*)d_ws;
  __bf16* xsplit = (__bf16*)(ws + 0);            // [4096][4096] = [x_hi | x_lo], 33.5 MB
  __bf16* qproj  = (__bf16*)(ws + 33554432);     // [4096][2048] bf16, 16.8 MB
  float*  kvproj = (float*)(ws + 50331648);      // [4096][1024] f32, 16.8 MB
  __bf16* wqT    = (__bf16*)(ws + 67108864);     // [2048][2048], 8.4 MB
  __bf16* wkvT   = (__bf16*)(ws + 75497472);     // [1024][6144] = [hi|hi|lo], 12.6 MB
  __bf16* wot    = (__bf16*)(ws + 88080384);     // [2048][2048], 8.4 MB
  __bf16* qbuf   = (__bf16*)(ws + 96468992);     // [16][4096][128], 16.8 MB
  __bf16* kbuf   = (__bf16*)(ws + 113246208);    // [4][4096][128], 4.2 MB
  __bf16* vbuf   = (__bf16*)(ws + 117440512);    // [4][128][4096], 4.2 MB
  __bf16* abuf   = (__bf16*)(ws + 0);            // reuses xsplit (dead after proj GEMMs)

  cast_x_split_kernel<<<4096, 256, 0, stream>>>(x, xsplit);
  transpose_cast_kernel<<<dim3(256, 32), 64, 0, stream>>>(Wq, wqT, 2048, 2048);
  transpose_split_kernel<<<dim3(256, 8), 64, 0, stream>>>(Wk, wkvT, 512);
  transpose_split_kernel<<<dim3(256, 8), 64, 0, stream>>>(Wv, wkvT + (size_t)512 * 6144, 512);
  transpose_cast_kernel<<<dim3(256, 32), 64, 0, stream>>>(Wo, wot, 2048, 2048);

  // q projection: plain bf16 (q is not quantized)
  gemm_kernel<true><<<dim3(16, 32), 256, 0, stream>>>(xsplit, wqT, qproj,
                                                      4096, 2048, 2048, 4096, 2048, 1 << 30);
  // k,v projection: 3-term split-bf16 (hi*hi + lo*hi + hi*lo), K=6144, A wraps at 4096.
  gemm_kernel<false><<<dim3(8, 32), 256, 0, stream>>>(xsplit, wkvT, kvproj,
                                                      4096, 1024, 6144, 4096, 6144, 4096);
  rope_norm_quant_kernel<<<dim3(4096, 6), 256, 0, stream>>>(qproj, kvproj, cosp, sinp,
                                                            qbuf, kbuf, vbuf);
  attn_kernel<<<2048, 128, 0, stream>>>(qbuf, kbuf, vbuf, abuf);
  // d_out is float32 (reference output dtype)
  gemm_kernel<false><<<dim3(16, 32), 256, 0, stream>>>(abuf, wot, d_out,
                                                       4096, 2048, 2048, 2048, 2048, 1 << 30);
}

// Round 6
// 514.410 us; speedup vs baseline: 1.0410x; 1.0410x over previous
//
#include <hip/hip_runtime.h>
#include <hip/hip_bf16.h>
#include <math.h>

// Problem constants
#define T_SEQ 4096
#define NEMB  2048
#define NH    16
#define NKV   4
#define HD    128
#define WIN   1024

typedef __attribute__((ext_vector_type(8))) __bf16 bf16x8;
typedef __attribute__((ext_vector_type(4))) __bf16 bf16x4;
typedef __attribute__((ext_vector_type(4))) float  f32x4;

// async global->LDS, 16B per lane; dest = wave-uniform base + lane*16
#define GLOAD_LDS16(gp, lp)                                          \
  __builtin_amdgcn_global_load_lds(                                  \
      (const __attribute__((address_space(1))) void*)(gp),           \
      (__attribute__((address_space(3))) void*)(lp), 16, 0, 0)

__device__ __forceinline__ float wave_sum64(float v) {
#pragma unroll
  for (int off = 1; off < 64; off <<= 1) v += __shfl_xor(v, off, 64);
  return v;
}
__device__ __forceinline__ float wave_max64(float v) {
#pragma unroll
  for (int off = 1; off < 64; off <<= 1) v = fmaxf(v, __shfl_xor(v, off, 64));
  return v;
}
__device__ __forceinline__ uint32_t pack_bf16x2(float a, float b) {
  union { __bf16 h[2]; uint32_t u; } u_;
  u_.h[0] = (__bf16)a; u_.h[1] = (__bf16)b;
  return u_.u;
}

// ---- cast+split x: xsplit[4096][4096] = [x_hi | x_lo], 8 elems/thread ----
__global__ __launch_bounds__(256) void cast_x_split_kernel(const float* __restrict__ src,
                                                           __bf16* __restrict__ dst) {
  int i = blockIdx.x * 256 + threadIdx.x;   // 1M groups of 8
  int row = i >> 8, colg = i & 255;         // 256 groups per 2048-col row
  const f32x4* s4 = (const f32x4*)src;
  f32x4 a = s4[2 * i], b = s4[2 * i + 1];
  bf16x8 hi, lo;
#pragma unroll
  for (int j = 0; j < 4; ++j) {
    hi[j] = (__bf16)a[j]; lo[j] = (__bf16)(a[j] - (float)hi[j]);
    hi[j + 4] = (__bf16)b[j]; lo[j + 4] = (__bf16)(b[j] - (float)hi[j + 4]);
  }
  *(bf16x8*)(dst + (size_t)row * 4096 + colg * 8) = hi;
  *(bf16x8*)(dst + (size_t)row * 4096 + 2048 + colg * 8) = lo;
}

// ------- transpose-cast: src f32 [K=2048][N] -> dst bf16 [N][2048] ------------
__global__ __launch_bounds__(64) void transpose_cast_kernel(const float* __restrict__ src,
                                                            __bf16* __restrict__ dst,
                                                            int K, int N) {
  int kc = blockIdx.x * 8;
  int n  = blockIdx.y * 64 + threadIdx.x;
  bf16x8 o;
#pragma unroll
  for (int j = 0; j < 8; ++j) o[j] = (__bf16)src[(size_t)(kc + j) * N + n];
  *(bf16x8*)(dst + (size_t)n * K + kc) = o;
}

// ---- transpose-split-cast: src f32 [2048][N] -> dst[n][0:2048]=hi,
// ---- dst[n][2048:4096]=hi, dst[n][4096:6144]=lo  (row stride ld=6144) ----
__global__ __launch_bounds__(64) void transpose_split_kernel(const float* __restrict__ src,
                                                             __bf16* __restrict__ dst,
                                                             int N) {
  int kc = blockIdx.x * 8;
  int n  = blockIdx.y * 64 + threadIdx.x;
  bf16x8 hi, lo;
#pragma unroll
  for (int j = 0; j < 8; ++j) {
    float v = src[(size_t)(kc + j) * N + n];
    hi[j] = (__bf16)v; lo[j] = (__bf16)(v - (float)hi[j]);
  }
  *(bf16x8*)(dst + (size_t)n * 6144 + kc) = hi;
  *(bf16x8*)(dst + (size_t)n * 6144 + 2048 + kc) = hi;
  *(bf16x8*)(dst + (size_t)n * 6144 + 4096 + kc) = lo;
}

// ---------------- bf16 MFMA GEMM: C[M,N] = A[M,K] * BT[N,K]^T ----------------
// m97/m201 structure: 128x128 tile, BK=64, 4 waves (2x2), 4x4 frags/wave.
// global_load_lds width=16, LINEAR LDS dest + PRE-SWIZZLED global source col
// (grp_src = (l&7) ^ ((l>>3)&7)) + XOR'd ds_read index (guide rule 21):
// turns the 16-way row-stride-128B read conflict into 2-way (free).
template <bool OUT_BF16>
__global__ __launch_bounds__(256) void gemm_kernel(const __bf16* __restrict__ A,
                                                   const __bf16* __restrict__ BT,
                                                   void* __restrict__ Cout,
                                                   int M, int N, int K,
                                                   int lda, int ldb, int awrap) {
  __shared__ __align__(16) __bf16 As[128 * 64];  // [row][col] linear dest
  __shared__ __align__(16) __bf16 Bs[128 * 64];
  const int tid = threadIdx.x;
  const int lane = tid & 63, w = tid >> 6;
  const int wr = w >> 1, wc = w & 1;
  const int g = lane >> 4, c = lane & 15;
  const int m0 = blockIdx.y * 128, n0 = blockIdx.x * 128;
  const int srow = lane >> 3;                       // row within 8-row chunk
  const int sgrp = (lane & 7) ^ (srow & 7);         // pre-swizzled 16B col group
  f32x4 acc[4][4] = {};
  for (int k0 = 0; k0 < K; k0 += 64) {
    int ka = k0 + sgrp * 8;
    int kaw = (ka >= awrap) ? ka - awrap : ka;      // BK block never straddles awrap
    __syncthreads();            // prev-iter LDS reads done before overwrite
#pragma unroll
    for (int i = 0; i < 4; ++i) {
      int chunk = w * 4 + i;               // 16 chunks of 8 rows
      int row = chunk * 8 + srow;
      GLOAD_LDS16(A  + (size_t)(m0 + row) * lda + kaw, As + chunk * 512);
      GLOAD_LDS16(BT + (size_t)(n0 + row) * ldb + ka,  Bs + chunk * 512);
    }
    __syncthreads();            // compiler drains vmcnt before barrier
#pragma unroll
    for (int kk = 0; kk < 2; ++kk) {
      bf16x8 af[4], bfr[4];
#pragma unroll
      for (int mi = 0; mi < 4; ++mi) {
        int row = wr * 64 + mi * 16 + c;
        af[mi] = *(const bf16x8*)&As[row * 64 + (((kk * 4 + g) ^ (row & 7)) * 8)];
      }
#pragma unroll
      for (int ni = 0; ni < 4; ++ni) {
        int row = wc * 64 + ni * 16 + c;
        bfr[ni] = *(const bf16x8*)&Bs[row * 64 + (((kk * 4 + g) ^ (row & 7)) * 8)];
      }
#pragma unroll
      for (int mi = 0; mi < 4; ++mi)
#pragma unroll
        for (int ni = 0; ni < 4; ++ni)
          acc[mi][ni] = __builtin_amdgcn_mfma_f32_16x16x32_bf16(af[mi], bfr[ni], acc[mi][ni], 0, 0, 0);
    }
  }
  // C frag layout: col = lane&15, row = (lane>>4)*4 + r   [m89-verified]
#pragma unroll
  for (int mi = 0; mi < 4; ++mi) {
#pragma unroll
    for (int ni = 0; ni < 4; ++ni) {
      int row = m0 + wr * 64 + mi * 16 + g * 4;
      int col = n0 + wc * 64 + ni * 16 + c;
#pragma unroll
      for (int r = 0; r < 4; ++r) {
        if constexpr (OUT_BF16)
          ((__bf16*)Cout)[(size_t)(row + r) * N + col] = (__bf16)acc[mi][ni][r];
        else
          ((float*)Cout)[(size_t)(row + r) * N + col] = acc[mi][ni][r];
      }
    }
  }
}

// -------- RoPE + RMSNorm (q,k) + quant-dequant (k,v), v stored transposed --------
__global__ __launch_bounds__(256) void rope_norm_quant_kernel(const __bf16* __restrict__ qproj,
                                                              const float* __restrict__ kvproj,
                                                              const float* __restrict__ cosp,
                                                              const float* __restrict__ sinp,
                                                              __bf16* __restrict__ qb,
                                                              __bf16* __restrict__ kb,
                                                              __bf16* __restrict__ vt) {
  const int t = blockIdx.x;
  const int w = threadIdx.x >> 6, lane = threadIdx.x & 63;
  const int slot = blockIdx.y * 4 + w;
  float a, b;
  if (slot < 16) {
    const __bf16* base = qproj + (size_t)t * 2048 + slot * 128;
    a = (float)base[lane]; b = (float)base[lane + 64];
  } else {
    const float* base = kvproj + (size_t)t * 1024 + (slot - 16) * 128;
    a = base[lane]; b = base[lane + 64];
  }
  float o1, o2;
  if (slot < 20) {  // rope + rmsnorm for q and k
    float cv = cosp[t * 64 + lane], sv = sinp[t * 64 + lane];
    o1 = a * cv + b * sv;
    o2 = -a * sv + b * cv;
    float ss = wave_sum64(o1 * o1 + o2 * o2);
    float sc = rsqrtf(ss * (1.0f / 128.0f) + 1.1920929e-7f);
    o1 *= sc; o2 *= sc;
  } else { o1 = a; o2 = b; }
  if (slot < 16) {
    __bf16* dst = qb + ((size_t)slot * T_SEQ + t) * HD;
    dst[lane] = (__bf16)o1; dst[lane + 64] = (__bf16)o2;
  } else {
    float amax = wave_max64(fmaxf(fabsf(o1), fabsf(o2)));
    float s = fmaxf(amax * (1.0f / 3.0f), 1e-8f);
    float d1 = fminf(fmaxf(rintf(o1 / s), -3.0f), 3.0f) * s;
    float d2 = fminf(fmaxf(rintf(o2 / s), -3.0f), 3.0f) * s;
    if (slot < 20) {
      __bf16* dst = kb + ((size_t)(slot - 16) * T_SEQ + t) * HD;
      dst[lane] = (__bf16)d1; dst[lane + 64] = (__bf16)d2;
    } else {
      __bf16* dst = vt + (size_t)(slot - 20) * HD * T_SEQ;   // [hkv][d][t]
      dst[(size_t)lane * T_SEQ + t]        = (__bf16)d1;
      dst[(size_t)(lane + 64) * T_SEQ + t] = (__bf16)d2;
    }
  }
}

// ---------- flash sliding-window attention, swapped-QK^T, zero LDS ----------
// S^T = mfma(K, Q): C-frag holds qrow=c, key=4g+r (operand loads identical to
// the unswapped form; A/B frags share the same sigma(lane,j) map). P^T is
// re-laid into the PV B-frag IN-REGISTER (pack bf16 pairs + fixed-pattern
// shfl across g-groups + ni select) -- no LDS roundtrip, no fences.
// PV = mfma(V^T, P^T) -> O^T (d=4g+r rows, qrow=c cols). No max-tracking
// (RMSNorm bounds |score*scl|<=~12.5; shift-invariance makes it exact).
__global__ __launch_bounds__(256) void attn_kernel(const __bf16* __restrict__ qb,
                                                   const __bf16* __restrict__ kb,
                                                   const __bf16* __restrict__ vt,
                                                   __bf16* __restrict__ attn) {
  const int w = threadIdx.x >> 6, lane = threadIdx.x & 63;
  const int g = lane >> 4, c = lane & 15;
  const int wg = blockIdx.x * 4 + w;
  const int h = wg >> 7, qt = wg & 127;
  const int q0 = qt * 32;
  const int hkv = h >> 2;
  const __bf16* kbase = kb + (size_t)hkv * T_SEQ * HD;
  const __bf16* vbase = vt + (size_t)hkv * HD * T_SEQ;
  const float scl = 0.08838834764831845f;  // 1/sqrt(128)

  // Q as B-frag: col=c -> qrow=q0+16mi+c; k=8g+j -> d=kc*32+8g+j
  bf16x8 qf[2][4];
#pragma unroll
  for (int mi = 0; mi < 2; ++mi)
#pragma unroll
    for (int kc = 0; kc < 4; ++kc)
      qf[mi][kc] = *(const bf16x8*)(qb + ((size_t)h * T_SEQ + q0 + 16 * mi + c) * HD + kc * 32 + 8 * g);

  f32x4 acc[2][8] = {};     // acc[mi][df]: O^T, row=4g+r -> d=df*16+4g+r, col=c -> qrow
  float lsum[2] = {};       // per-lane row-sum for qrow=q0+16mi+c (partial over g's keys)

  const int srcLow = ((g & 1) << 5) + c;   // shfl sources for P^T B-frag build
  const int srcHigh = srcLow + 16;
  const bool gHi = g >= 2;                  // ni select

  int lo = q0 - (WIN - 1);
  if (lo < 0) lo = 0;
  lo &= ~31;
  for (int kj0 = lo; kj0 <= q0 + 31; kj0 += 32) {
    // V^T A-frags: row=c -> d=df*16+c; k=8g+j -> key=kj0+8g+j (contiguous 16B)
    bf16x8 vf[8];
#pragma unroll
    for (int df = 0; df < 8; ++df)
      vf[df] = *(const bf16x8*)(vbase + (size_t)(df * 16 + c) * T_SEQ + kj0 + 8 * g);
    // S^T = K*Q^T: st[ni][mi], A=K-frag (row=c -> key=kj0+16ni+c)
    f32x4 st[2][2] = {};
#pragma unroll
    for (int kc = 0; kc < 4; ++kc) {
      bf16x8 bk0 = *(const bf16x8*)(kbase + (size_t)(kj0 + c) * HD + kc * 32 + 8 * g);
      bf16x8 bk1 = *(const bf16x8*)(kbase + (size_t)(kj0 + 16 + c) * HD + kc * 32 + 8 * g);
#pragma unroll
      for (int mi = 0; mi < 2; ++mi) {
        st[0][mi] = __builtin_amdgcn_mfma_f32_16x16x32_bf16(bk0, qf[mi][kc], st[0][mi], 0, 0, 0);
        st[1][mi] = __builtin_amdgcn_mfma_f32_16x16x32_bf16(bk1, qf[mi][kc], st[1][mi], 0, 0, 0);
      }
    }
    // mask + exp: qrow=q0+16mi+c, key=kj0+16ni+4g+r
    float p[2][2][4];
#pragma unroll
    for (int ni = 0; ni < 2; ++ni)
#pragma unroll
      for (int mi = 0; mi < 2; ++mi)
#pragma unroll
        for (int r = 0; r < 4; ++r) {
          int qrow = q0 + 16 * mi + c;
          int key = kj0 + 16 * ni + 4 * g + r;
          int d = qrow - key;
          float e = __expf(st[ni][mi][r] * scl);
          p[ni][mi][r] = (d >= 0 && d < WIN) ? e : 0.0f;
        }
#pragma unroll
    for (int mi = 0; mi < 2; ++mi)
      lsum[mi] += (p[0][mi][0] + p[0][mi][1] + p[0][mi][2] + p[0][mi][3]) +
                  (p[1][mi][0] + p[1][mi][1] + p[1][mi][2] + p[1][mi][3]);
    // pack P^T to bf16 u32 pairs, build PV B-frag in-register:
    // target lane(g,c) needs keys 8g+j at qrow c: ni=g>>1, src lanes
    // (2*(g&1))*16+c and +16; j0-1/2-3 from srcLow pk0/pk1, j4-7 from srcHigh.
#pragma unroll
    for (int mi = 0; mi < 2; ++mi) {
      uint32_t pk00 = pack_bf16x2(p[0][mi][0], p[0][mi][1]);
      uint32_t pk01 = pack_bf16x2(p[0][mi][2], p[0][mi][3]);
      uint32_t pk10 = pack_bf16x2(p[1][mi][0], p[1][mi][1]);
      uint32_t pk11 = pack_bf16x2(p[1][mi][2], p[1][mi][3]);
      uint32_t n0a = __shfl((int)pk00, srcLow),  n0b = __shfl((int)pk01, srcLow);
      uint32_t n0c = __shfl((int)pk00, srcHigh), n0d = __shfl((int)pk01, srcHigh);
      uint32_t n1a = __shfl((int)pk10, srcLow),  n1b = __shfl((int)pk11, srcLow);
      uint32_t n1c = __shfl((int)pk10, srcHigh), n1d = __shfl((int)pk11, srcHigh);
      union { uint32_t u[4]; bf16x8 v; } bu;
      bu.u[0] = gHi ? n1a : n0a;
      bu.u[1] = gHi ? n1b : n0b;
      bu.u[2] = gHi ? n1c : n0c;
      bu.u[3] = gHi ? n1d : n0d;
      // PV: acc[mi][df] += V^T * P^T
#pragma unroll
      for (int df = 0; df < 8; ++df)
        acc[mi][df] = __builtin_amdgcn_mfma_f32_16x16x32_bf16(vf[df], bu.v, acc[mi][df], 0, 0, 0);
    }
  }
  // finish row-sums (reduce across g: lanes differing in bits 4,5), normalize, store
#pragma unroll
  for (int mi = 0; mi < 2; ++mi) {
    lsum[mi] += __shfl_xor(lsum[mi], 16, 64);
    lsum[mi] += __shfl_xor(lsum[mi], 32, 64);
    float inv = 1.0f / lsum[mi];
#pragma unroll
    for (int df = 0; df < 8; ++df) {
      bf16x4 o;
#pragma unroll
      for (int r = 0; r < 4; ++r) o[r] = (__bf16)(acc[mi][df][r] * inv);
      // O^T: d = df*16 + 4g + r (consecutive r -> consecutive d), qrow = q0+16mi+c
      *(bf16x4*)(attn + (size_t)(q0 + 16 * mi + c) * NEMB + h * HD + df * 16 + 4 * g) = o;
    }
  }
}

extern "C" void kernel_launch(void* const* d_in, const int* in_sizes, int n_in,
                              void* d_out, int out_size, void* d_ws, size_t ws_size,
                              hipStream_t stream) {
  (void)in_sizes; (void)n_in; (void)out_size; (void)ws_size;
  const float* x    = (const float*)d_in[0];
  const float* cosp = (const float*)d_in[1];
  const float* sinp = (const float*)d_in[2];
  const float* Wq   = (const float*)d_in[3];
  const float* Wk   = (const float*)d_in[4];
  const float* Wv   = (const float*)d_in[5];
  const float* Wo   = (const float*)d_in[6];

  // workspace layout (bytes); total = 121,634,816
  char* ws = (char*)d_ws;
  __bf16* xsplit = (__bf16*)(ws + 0);            // [4096][4096] = [x_hi | x_lo], 33.5 MB
  __bf16* qproj  = (__bf16*)(ws + 33554432);     // [4096][2048] bf16, 16.8 MB
  float*  kvproj = (float*)(ws + 50331648);      // [4096][1024] f32, 16.8 MB
  __bf16* wqT    = (__bf16*)(ws + 67108864);     // [2048][2048], 8.4 MB
  __bf16* wkvT   = (__bf16*)(ws + 75497472);     // [1024][6144] = [hi|hi|lo], 12.6 MB
  __bf16* wot    = (__bf16*)(ws + 88080384);     // [2048][2048], 8.4 MB
  __bf16* qbuf   = (__bf16*)(ws + 96468992);     // [16][4096][128], 16.8 MB
  __bf16* kbuf   = (__bf16*)(ws + 113246208);    // [4][4096][128], 4.2 MB
  __bf16* vbuf   = (__bf16*)(ws + 117440512);    // [4][128][4096], 4.2 MB
  __bf16* abuf   = (__bf16*)(ws + 0);            // reuses xsplit (dead after proj GEMMs)

  cast_x_split_kernel<<<4096, 256, 0, stream>>>(x, xsplit);
  transpose_cast_kernel<<<dim3(256, 32), 64, 0, stream>>>(Wq, wqT, 2048, 2048);
  transpose_split_kernel<<<dim3(256, 8), 64, 0, stream>>>(Wk, wkvT, 512);
  transpose_split_kernel<<<dim3(256, 8), 64, 0, stream>>>(Wv, wkvT + (size_t)512 * 6144, 512);
  transpose_cast_kernel<<<dim3(256, 32), 64, 0, stream>>>(Wo, wot, 2048, 2048);

  // q projection: plain bf16 (q is not quantized)
  gemm_kernel<true><<<dim3(16, 32), 256, 0, stream>>>(xsplit, wqT, qproj,
                                                      4096, 2048, 2048, 4096, 2048, 1 << 30);
  // k,v projection: 3-term split-bf16 (hi*hi + lo*hi + hi*lo), K=6144, A wraps at 4096.
  gemm_kernel<false><<<dim3(8, 32), 256, 0, stream>>>(xsplit, wkvT, kvproj,
                                                      4096, 1024, 6144, 4096, 6144, 4096);
  rope_norm_quant_kernel<<<dim3(4096, 6), 256, 0, stream>>>(qproj, kvproj, cosp, sinp,
                                                            qbuf, kbuf, vbuf);
  attn_kernel<<<512, 256, 0, stream>>>(qbuf, kbuf, vbuf, abuf);
  // d_out is float32 (reference output dtype)
  gemm_kernel<false><<<dim3(16, 32), 256, 0, stream>>>(abuf, wot, d_out,
                                                       4096, 2048, 2048, 2048, 2048, 1 << 30);
}

// Round 8
// 434.675 us; speedup vs baseline: 1.2320x; 1.1834x over previous
//
#include <hip/hip_runtime.h>
#include <hip/hip_bf16.h>
#include <math.h>

// Problem constants
#define T_SEQ 4096
#define NEMB  2048
#define NH    16
#define NKV   4
#define HD    128
#define WIN   1024

typedef __attribute__((ext_vector_type(8))) __bf16 bf16x8;
typedef __attribute__((ext_vector_type(4))) __bf16 bf16x4;
typedef __attribute__((ext_vector_type(4))) float  f32x4;

// async global->LDS, 16B per lane; dest = wave-uniform base + lane*16
#define GLOAD_LDS16(gp, lp)                                          \
  __builtin_amdgcn_global_load_lds(                                  \
      (const __attribute__((address_space(1))) void*)(gp),           \
      (__attribute__((address_space(3))) void*)(lp), 16, 0, 0)

__device__ __forceinline__ float wave_sum64(float v) {
#pragma unroll
  for (int off = 1; off < 64; off <<= 1) v += __shfl_xor(v, off, 64);
  return v;
}
__device__ __forceinline__ float wave_max64(float v) {
#pragma unroll
  for (int off = 1; off < 64; off <<= 1) v = fmaxf(v, __shfl_xor(v, off, 64));
  return v;
}
__device__ __forceinline__ uint32_t pack_bf16x2(float a, float b) {
  union { __bf16 h[2]; uint32_t u; } u_;
  u_.h[0] = (__bf16)a; u_.h[1] = (__bf16)b;
  return u_.u;
}

// ---- cast+split x: xsplit[4096][4096] = [x_hi | x_lo], 8 elems/thread ----
__global__ __launch_bounds__(256) void cast_x_split_kernel(const float* __restrict__ src,
                                                           __bf16* __restrict__ dst) {
  int i = blockIdx.x * 256 + threadIdx.x;   // 1M groups of 8
  int row = i >> 8, colg = i & 255;         // 256 groups per 2048-col row
  const f32x4* s4 = (const f32x4*)src;
  f32x4 a = s4[2 * i], b = s4[2 * i + 1];
  bf16x8 hi, lo;
#pragma unroll
  for (int j = 0; j < 4; ++j) {
    hi[j] = (__bf16)a[j]; lo[j] = (__bf16)(a[j] - (float)hi[j]);
    hi[j + 4] = (__bf16)b[j]; lo[j + 4] = (__bf16)(b[j] - (float)hi[j + 4]);
  }
  *(bf16x8*)(dst + (size_t)row * 4096 + colg * 8) = hi;
  *(bf16x8*)(dst + (size_t)row * 4096 + 2048 + colg * 8) = lo;
}

// ------- transpose-cast: src f32 [K=2048][N] -> dst bf16 [N][2048] ------------
__global__ __launch_bounds__(64) void transpose_cast_kernel(const float* __restrict__ src,
                                                            __bf16* __restrict__ dst,
                                                            int K, int N) {
  int kc = blockIdx.x * 8;
  int n  = blockIdx.y * 64 + threadIdx.x;
  bf16x8 o;
#pragma unroll
  for (int j = 0; j < 8; ++j) o[j] = (__bf16)src[(size_t)(kc + j) * N + n];
  *(bf16x8*)(dst + (size_t)n * K + kc) = o;
}

// ---- transpose-split-cast: src f32 [2048][N] -> dst[n][0:2048]=hi,
// ---- dst[n][2048:4096]=hi, dst[n][4096:6144]=lo  (row stride ld=6144) ----
__global__ __launch_bounds__(64) void transpose_split_kernel(const float* __restrict__ src,
                                                             __bf16* __restrict__ dst,
                                                             int N) {
  int kc = blockIdx.x * 8;
  int n  = blockIdx.y * 64 + threadIdx.x;
  bf16x8 hi, lo;
#pragma unroll
  for (int j = 0; j < 8; ++j) {
    float v = src[(size_t)(kc + j) * N + n];
    hi[j] = (__bf16)v; lo[j] = (__bf16)(v - (float)hi[j]);
  }
  *(bf16x8*)(dst + (size_t)n * 6144 + kc) = hi;
  *(bf16x8*)(dst + (size_t)n * 6144 + 2048 + kc) = hi;
  *(bf16x8*)(dst + (size_t)n * 6144 + 4096 + kc) = lo;
}

// ---------------- bf16 MFMA GEMM: C[M,N] = A[M,K] * BT[N,K]^T ----------------
// 128xBN tile (BN=128 or 64), BK=64, 4 waves (2x2). global_load_lds width=16,
// linear LDS dest + pre-swizzled global source + XOR'd ds_read (rule 21).
// Chunked bijective XCD swizzle on the linear block id (nwg % 8 == 0).
template <bool OUT_BF16, int BN>
__global__ __launch_bounds__(256) void gemm_kernel(const __bf16* __restrict__ A,
                                                   const __bf16* __restrict__ BT,
                                                   void* __restrict__ Cout,
                                                   int M, int N, int K,
                                                   int lda, int ldb, int awrap) {
  constexpr int NI = BN / 32;                       // B frags per wave
  __shared__ __align__(16) __bf16 As[128 * 64];
  __shared__ __align__(16) __bf16 Bs[BN * 64];
  const int tid = threadIdx.x;
  const int lane = tid & 63, w = tid >> 6;
  const int wr = w >> 1, wc = w & 1;
  const int g = lane >> 4, c = lane & 15;
  const int nwg = gridDim.x * gridDim.y;
  int idx = blockIdx.y * gridDim.x + blockIdx.x;
  idx = (idx & 7) * (nwg >> 3) + (idx >> 3);        // XCD chunked, bijective
  const int bx = idx % gridDim.x, by = idx / gridDim.x;
  const int m0 = by * 128, n0 = bx * BN;
  const int srow = lane >> 3;                       // row within 8-row chunk
  const int sgrp = (lane & 7) ^ (srow & 7);         // pre-swizzled 16B col group
  f32x4 acc[4][4] = {};
  for (int k0 = 0; k0 < K; k0 += 64) {
    int ka = k0 + sgrp * 8;
    int kaw = (ka >= awrap) ? ka - awrap : ka;      // BK block never straddles awrap
    __syncthreads();            // prev-iter LDS reads done before overwrite
#pragma unroll
    for (int i = 0; i < 4; ++i) {
      int chunk = w * 4 + i;               // 16 chunks of 8 rows (A: 128 rows)
      int row = chunk * 8 + srow;
      GLOAD_LDS16(A + (size_t)(m0 + row) * lda + kaw, As + chunk * 512);
    }
#pragma unroll
    for (int i = 0; i < NI; ++i) {
      int chunk = w * NI + i;              // BN/8 chunks of 8 rows
      int row = chunk * 8 + srow;
      GLOAD_LDS16(BT + (size_t)(n0 + row) * ldb + ka, Bs + chunk * 512);
    }
    __syncthreads();            // compiler drains vmcnt before barrier
#pragma unroll
    for (int kk = 0; kk < 2; ++kk) {
      bf16x8 af[4], bfr[NI];
#pragma unroll
      for (int mi = 0; mi < 4; ++mi) {
        int row = wr * 64 + mi * 16 + c;
        af[mi] = *(const bf16x8*)&As[row * 64 + (((kk * 4 + g) ^ (row & 7)) * 8)];
      }
#pragma unroll
      for (int ni = 0; ni < NI; ++ni) {
        int row = wc * (BN / 2) + ni * 16 + c;
        bfr[ni] = *(const bf16x8*)&Bs[row * 64 + (((kk * 4 + g) ^ (row & 7)) * 8)];
      }
#pragma unroll
      for (int mi = 0; mi < 4; ++mi)
#pragma unroll
        for (int ni = 0; ni < NI; ++ni)
          acc[mi][ni] = __builtin_amdgcn_mfma_f32_16x16x32_bf16(af[mi], bfr[ni], acc[mi][ni], 0, 0, 0);
    }
  }
  // C frag layout: col = lane&15, row = (lane>>4)*4 + r   [m89-verified]
#pragma unroll
  for (int mi = 0; mi < 4; ++mi) {
#pragma unroll
    for (int ni = 0; ni < NI; ++ni) {
      int row = m0 + wr * 64 + mi * 16 + g * 4;
      int col = n0 + wc * (BN / 2) + ni * 16 + c;
#pragma unroll
      for (int r = 0; r < 4; ++r) {
        if constexpr (OUT_BF16)
          ((__bf16*)Cout)[(size_t)(row + r) * N + col] = (__bf16)acc[mi][ni][r];
        else
          ((float*)Cout)[(size_t)(row + r) * N + col] = acc[mi][ni][r];
      }
    }
  }
}

// -------- RoPE + RMSNorm (q,k) + quant-dequant (k,v), v stored transposed --------
__global__ __launch_bounds__(256) void rope_norm_quant_kernel(const __bf16* __restrict__ qproj,
                                                              const float* __restrict__ kvproj,
                                                              const float* __restrict__ cosp,
                                                              const float* __restrict__ sinp,
                                                              __bf16* __restrict__ qb,
                                                              __bf16* __restrict__ kb,
                                                              __bf16* __restrict__ vt) {
  const int t = blockIdx.x;
  const int w = threadIdx.x >> 6, lane = threadIdx.x & 63;
  const int slot = blockIdx.y * 4 + w;
  float a, b;
  if (slot < 16) {
    const __bf16* base = qproj + (size_t)t * 2048 + slot * 128;
    a = (float)base[lane]; b = (float)base[lane + 64];
  } else {
    const float* base = kvproj + (size_t)t * 1024 + (slot - 16) * 128;
    a = base[lane]; b = base[lane + 64];
  }
  float o1, o2;
  if (slot < 20) {  // rope + rmsnorm for q and k
    float cv = cosp[t * 64 + lane], sv = sinp[t * 64 + lane];
    o1 = a * cv + b * sv;
    o2 = -a * sv + b * cv;
    float ss = wave_sum64(o1 * o1 + o2 * o2);
    float sc = rsqrtf(ss * (1.0f / 128.0f) + 1.1920929e-7f);
    o1 *= sc; o2 *= sc;
  } else { o1 = a; o2 = b; }
  if (slot < 16) {
    __bf16* dst = qb + ((size_t)slot * T_SEQ + t) * HD;
    dst[lane] = (__bf16)o1; dst[lane + 64] = (__bf16)o2;
  } else {
    float amax = wave_max64(fmaxf(fabsf(o1), fabsf(o2)));
    float s = fmaxf(amax * (1.0f / 3.0f), 1e-8f);
    float d1 = fminf(fmaxf(rintf(o1 / s), -3.0f), 3.0f) * s;
    float d2 = fminf(fmaxf(rintf(o2 / s), -3.0f), 3.0f) * s;
    if (slot < 20) {
      __bf16* dst = kb + ((size_t)(slot - 16) * T_SEQ + t) * HD;
      dst[lane] = (__bf16)d1; dst[lane + 64] = (__bf16)d2;
    } else {
      __bf16* dst = vt + (size_t)(slot - 20) * HD * T_SEQ;   // [hkv][d][t]
      dst[(size_t)lane * T_SEQ + t]        = (__bf16)d1;
      dst[(size_t)(lane + 64) * T_SEQ + t] = (__bf16)d2;
    }
  }
}

// ---------- flash sliding-window attention: LDS-staged K/V, swapped QK^T ----------
// Block = 4 waves = 4 consecutive 32-row q-tiles of ONE head sharing a union
// key-window. Per 32-key step: K(32x128) and V^T(128x32) staged coalesced via
// global_load_lds (linear dest + inverse-swizzled global source, XOR'd ds_read
// -- rule 21), double-buffered, prefetch-next + single vmcnt(0)+barrier.
// r7 bug fixed: K-tile row stride is 128 bf16 (r*128), not the GEMM's 64.
__global__ __launch_bounds__(256) void attn_kernel(const __bf16* __restrict__ qb,
                                                   const __bf16* __restrict__ kb,
                                                   const __bf16* __restrict__ vt,
                                                   __bf16* __restrict__ attn) {
  __shared__ __align__(16) __bf16 Ks[2][32 * 128];   // 8 KB each
  __shared__ __align__(16) __bf16 Vs[2][128 * 32];   // 8 KB each
  const int w = threadIdx.x >> 6, lane = threadIdx.x & 63;
  const int g = lane >> 4, c = lane & 15;
  // XCD swizzle (512 blocks, 8 XCDs): each XCD serves 2 heads -> K/V L2-resident
  const int bid = (blockIdx.x & 7) * 64 + (blockIdx.x >> 3);
  const int h = bid >> 5, st = bid & 31;
  const int Q0 = st * 128;
  const int q0 = Q0 + 32 * w;
  const int hkv = h >> 2;
  const __bf16* kbase = kb + (size_t)hkv * T_SEQ * HD;
  const __bf16* vbase = vt + (size_t)hkv * HD * T_SEQ;
  const float scl = 0.08838834764831845f;  // 1/sqrt(128)

  // Q as B-frag: col=c -> qrow=q0+16mi+c; k=8g+j -> d=kc*32+8g+j
  bf16x8 qf[2][4];
#pragma unroll
  for (int mi = 0; mi < 2; ++mi)
#pragma unroll
    for (int kc = 0; kc < 4; ++kc)
      qf[mi][kc] = *(const bf16x8*)(qb + ((size_t)h * T_SEQ + q0 + 16 * mi + c) * HD + kc * 32 + 8 * g);

  f32x4 acc[2][8] = {};     // O^T: row 4g+r -> d=df*16+4g+r, col c -> qrow
  float lsum[2] = {};

  const int srcLow = ((g & 1) << 5) + c;   // shfl sources for P^T B-frag build
  const int srcHigh = srcLow + 16;
  const bool gHi = g >= 2;

  int lo = Q0 - (WIN - 1);
  if (lo < 0) lo = 0;
  lo &= ~31;
  const int kjEnd = Q0 + 96;               // last 32-key step start for the block

  // staging: K tile = 512 x 16B slots; slot s: row=s>>4, gl=s&15 holds logical
  // grp gl^(row&7). V tile: slot s: d=s>>2, gl=s&3 holds logical grp gl^(d&3).
  auto stage = [&](int buf, int kj0) {
#pragma unroll
    for (int cl = 0; cl < 2; ++cl) {
      int s0 = cl * 256 + w * 64;          // wave-uniform base slot
      int s = s0 + lane;
      int krow = s >> 4, kgl = s & 15;
      GLOAD_LDS16(kbase + (size_t)(kj0 + krow) * HD + ((kgl ^ (krow & 7)) << 3),
                  &Ks[buf][(size_t)s0 * 8]);
      int vd = s >> 2, vgl = s & 3;
      GLOAD_LDS16(vbase + (size_t)vd * T_SEQ + kj0 + ((vgl ^ (vd & 3)) << 3),
                  &Vs[buf][(size_t)s0 * 8]);
    }
  };

  stage(0, lo);
  asm volatile("s_waitcnt vmcnt(0)" ::: "memory");
  __syncthreads();
  int cur = 0;
  for (int kj0 = lo; kj0 <= kjEnd; kj0 += 32) {
    if (kj0 < kjEnd) stage(cur ^ 1, kj0 + 32);   // prefetch next tile (other buf)
    // wave-uniform activity: step overlaps this wave's window [q0-1023, q0+31]
    if (kj0 >= q0 - 1054 && kj0 <= q0 + 31) {
      // V^T A-frags: row=c -> d=df*16+c; k=8g+j -> key=kj0+8g+j
      bf16x8 vf[8];
#pragma unroll
      for (int df = 0; df < 8; ++df) {
        int d = df * 16 + c;
        vf[df] = *(const bf16x8*)&Vs[cur][d * 32 + ((g ^ (d & 3)) << 3)];
      }
      // S^T = K*Q^T: st[ni][mi], A=K-frag (row=c -> key=kj0+16ni+c)
      f32x4 st_[2][2] = {};
#pragma unroll
      for (int kc = 0; kc < 4; ++kc) {
        int r0 = c, r1 = 16 + c;
        bf16x8 bk0 = *(const bf16x8*)&Ks[cur][r0 * 128 + (((4 * kc + g) ^ (r0 & 7)) << 3)];
        bf16x8 bk1 = *(const bf16x8*)&Ks[cur][r1 * 128 + (((4 * kc + g) ^ (r1 & 7)) << 3)];
#pragma unroll
        for (int mi = 0; mi < 2; ++mi) {
          st_[0][mi] = __builtin_amdgcn_mfma_f32_16x16x32_bf16(bk0, qf[mi][kc], st_[0][mi], 0, 0, 0);
          st_[1][mi] = __builtin_amdgcn_mfma_f32_16x16x32_bf16(bk1, qf[mi][kc], st_[1][mi], 0, 0, 0);
        }
      }
      // mask + exp: qrow=q0+16mi+c, key=kj0+16ni+4g+r
      float p[2][2][4];
#pragma unroll
      for (int ni = 0; ni < 2; ++ni)
#pragma unroll
        for (int mi = 0; mi < 2; ++mi)
#pragma unroll
          for (int r = 0; r < 4; ++r) {
            int qrow = q0 + 16 * mi + c;
            int key = kj0 + 16 * ni + 4 * g + r;
            int d = qrow - key;
            float e = __expf(st_[ni][mi][r] * scl);
            p[ni][mi][r] = (d >= 0 && d < WIN) ? e : 0.0f;
          }
#pragma unroll
      for (int mi = 0; mi < 2; ++mi)
        lsum[mi] += (p[0][mi][0] + p[0][mi][1] + p[0][mi][2] + p[0][mi][3]) +
                    (p[1][mi][0] + p[1][mi][1] + p[1][mi][2] + p[1][mi][3]);
      // pack P^T, build PV B-frag in-register (fixed shfl pattern + ni select)
#pragma unroll
      for (int mi = 0; mi < 2; ++mi) {
        uint32_t pk00 = pack_bf16x2(p[0][mi][0], p[0][mi][1]);
        uint32_t pk01 = pack_bf16x2(p[0][mi][2], p[0][mi][3]);
        uint32_t pk10 = pack_bf16x2(p[1][mi][0], p[1][mi][1]);
        uint32_t pk11 = pack_bf16x2(p[1][mi][2], p[1][mi][3]);
        uint32_t n0a = __shfl((int)pk00, srcLow),  n0b = __shfl((int)pk01, srcLow);
        uint32_t n0c = __shfl((int)pk00, srcHigh), n0d = __shfl((int)pk01, srcHigh);
        uint32_t n1a = __shfl((int)pk10, srcLow),  n1b = __shfl((int)pk11, srcLow);
        uint32_t n1c = __shfl((int)pk10, srcHigh), n1d = __shfl((int)pk11, srcHigh);
        union { uint32_t u[4]; bf16x8 v; } bu;
        bu.u[0] = gHi ? n1a : n0a;
        bu.u[1] = gHi ? n1b : n0b;
        bu.u[2] = gHi ? n1c : n0c;
        bu.u[3] = gHi ? n1d : n0d;
#pragma unroll
        for (int df = 0; df < 8; ++df)
          acc[mi][df] = __builtin_amdgcn_mfma_f32_16x16x32_bf16(vf[df], bu.v, acc[mi][df], 0, 0, 0);
      }
    }
    asm volatile("s_waitcnt vmcnt(0)" ::: "memory");  // next tile staged
    __syncthreads();
    cur ^= 1;
  }
  // finish row-sums (reduce across g), normalize, store O^T
#pragma unroll
  for (int mi = 0; mi < 2; ++mi) {
    lsum[mi] += __shfl_xor(lsum[mi], 16, 64);
    lsum[mi] += __shfl_xor(lsum[mi], 32, 64);
    float inv = 1.0f / lsum[mi];
#pragma unroll
    for (int df = 0; df < 8; ++df) {
      bf16x4 o;
#pragma unroll
      for (int r = 0; r < 4; ++r) o[r] = (__bf16)(acc[mi][df][r] * inv);
      *(bf16x4*)(attn + (size_t)(q0 + 16 * mi + c) * NEMB + h * HD + df * 16 + 4 * g) = o;
    }
  }
}

extern "C" void kernel_launch(void* const* d_in, const int* in_sizes, int n_in,
                              void* d_out, int out_size, void* d_ws, size_t ws_size,
                              hipStream_t stream) {
  (void)in_sizes; (void)n_in; (void)out_size; (void)ws_size;
  const float* x    = (const float*)d_in[0];
  const float* cosp = (const float*)d_in[1];
  const float* sinp = (const float*)d_in[2];
  const float* Wq   = (const float*)d_in[3];
  const float* Wk   = (const float*)d_in[4];
  const float* Wv   = (const float*)d_in[5];
  const float* Wo   = (const float*)d_in[6];

  // workspace layout (bytes); total = 121,634,816
  char* ws = (char*)d_ws;
  __bf16* xsplit = (__bf16*)(ws + 0);            // [4096][4096] = [x_hi | x_lo], 33.5 MB
  __bf16* qproj  = (__bf16*)(ws + 33554432);     // [4096][2048] bf16, 16.8 MB
  float*  kvproj = (float*)(ws + 50331648);      // [4096][1024] f32, 16.8 MB
  __bf16* wqT    = (__bf16*)(ws + 67108864);     // [2048][2048], 8.4 MB
  __bf16* wkvT   = (__bf16*)(ws + 75497472);     // [1024][6144] = [hi|hi|lo], 12.6 MB
  __bf16* wot    = (__bf16*)(ws + 88080384);     // [2048][2048], 8.4 MB
  __bf16* qbuf   = (__bf16*)(ws + 96468992);     // [16][4096][128], 16.8 MB
  __bf16* kbuf   = (__bf16*)(ws + 113246208);    // [4][4096][128], 4.2 MB
  __bf16* vbuf   = (__bf16*)(ws + 117440512);    // [4][128][4096], 4.2 MB
  __bf16* abuf   = (__bf16*)(ws + 0);            // reuses xsplit (dead after proj GEMMs)

  cast_x_split_kernel<<<4096, 256, 0, stream>>>(x, xsplit);
  transpose_cast_kernel<<<dim3(256, 32), 64, 0, stream>>>(Wq, wqT, 2048, 2048);
  transpose_split_kernel<<<dim3(256, 8), 64, 0, stream>>>(Wk, wkvT, 512);
  transpose_split_kernel<<<dim3(256, 8), 64, 0, stream>>>(Wv, wkvT + (size_t)512 * 6144, 512);
  transpose_cast_kernel<<<dim3(256, 32), 64, 0, stream>>>(Wo, wot, 2048, 2048);

  // q projection: plain bf16, BN=64 -> 1024 wgs (4 blocks/CU)
  gemm_kernel<true, 64><<<dim3(32, 32), 256, 0, stream>>>(xsplit, wqT, qproj,
                                                          4096, 2048, 2048, 4096, 2048, 1 << 30);
  // k,v projection: 3-term split-bf16, K=6144 (A wraps at 4096), BN=64 -> 512 wgs
  gemm_kernel<false, 64><<<dim3(16, 32), 256, 0, stream>>>(xsplit, wkvT, kvproj,
                                                           4096, 1024, 6144, 4096, 6144, 4096);
  rope_norm_quant_kernel<<<dim3(4096, 6), 256, 0, stream>>>(qproj, kvproj, cosp, sinp,
                                                            qbuf, kbuf, vbuf);
  attn_kernel<<<512, 256, 0, stream>>>(qbuf, kbuf, vbuf, abuf);
  // d_out is float32; BN=64 -> 1024 wgs
  gemm_kernel<false, 64><<<dim3(32, 32), 256, 0, stream>>>(abuf, wot, d_out,
                                                           4096, 2048, 2048, 2048, 2048, 1 << 30);
}